// Round 14
// baseline (371.003 us; speedup 1.0000x reference)
//
#include <hip/hip_runtime.h>
#include <hip/hip_bf16.h>
#include <stdint.h>

#define HID 128
#define NB 16384
#define TSTEPS 28
#define BN 32

typedef __attribute__((ext_vector_type(8))) short s16x8;
typedef __attribute__((ext_vector_type(4))) float f32x4;

// ---- LDS map (22.5KB -> 2 blocks/CU) ----
#define H1_OFF 0
#define H0_OFF 8704
#define XT_OFF 17408
#define SMEM_BYTES 22528
#define HSTRIDE 272
#define RFSTRIDE 4352   // 16*HSTRIDE
#define XSTRIDE 80

#define L2E 1.442695041f
#define TL2E 2.885390082f

__device__ __forceinline__ unsigned cvtpk2(float lo, float hi) {
  unsigned r;
  asm("v_cvt_pk_bf16_f32 %0, %1, %2" : "=v"(r) : "v"(lo), "v"(hi));
  return r;
}
__device__ __forceinline__ float sig_pre(float acc, float nb) {
  float e = __builtin_amdgcn_exp2f(fmaf(acc, -L2E, nb));
  return __builtin_amdgcn_rcpf(1.0f + e);
}
__device__ __forceinline__ float tanh_nc(float x) {
  float e2 = __builtin_amdgcn_exp2f(x * TL2E);
  float q = __builtin_amdgcn_rcpf(1.0f + e2);
  return fmaf(-2.0f, q, 1.0f);
}

// ---- prep: Wih2 (96 slots) + Wih1 (24 slots @ +98304) -> bf16 B-frags ----
__global__ void prep_w(const float* __restrict__ Wih2,
                       const float* __restrict__ Wih1,
                       char* __restrict__ ws) {
  const int b = blockIdx.x;
  const int lane = threadIdx.x;
  if (b < 96) {
    const int cb = b % 3, kf = (b / 3) & 3, cw = b / 12;
    const int g = cb * 128 + cw * 16 + (lane & 15);
    const float* p = Wih2 + g * HID + kf * 32 + (lane >> 4) * 8;
    s16x8 f;
    #pragma unroll
    for (int j = 0; j < 8; j += 2) {
      unsigned u = cvtpk2(p[j], p[j + 1]);
      f[j] = (short)u; f[j + 1] = (short)(u >> 16);
    }
    *(s16x8*)(ws + (b * 64 + lane) * 16) = f;
  } else {
    const int s = b - 96;               // 0..23
    const int cb = s % 3, cw = s / 3;
    const int g = cb * 128 + cw * 16 + (lane & 15);
    s16x8 f;
    #pragma unroll
    for (int j = 0; j < 8; ++j) {
      int k = (lane >> 4) * 8 + j;
      f[j] = (k < 28) ? (short)cvtpk2(Wih1[g * 28 + k], 0.f) : (short)0;
    }
    *(s16x8*)(ws + 98304 + (s * 64 + lane) * 16) = f;
  }
}

// ---- Design ledger (R3..R13) ----
// R13 (2 blocks/CU via ws-streamed Wih2) regressed from spill: (512,4) ->
// 64 arch + 64 acc; AGPR full (48 whh1 + 16 acc), cell2 peak (24 B-dbuf +
// 24 acc + persist) overran arch -> 11.9MB scratch. R14 fixes the ledger:
//  - fw_ih1 also streamed from ws (-12 persistent arch),
//  - cell2 single-p passes: acc 24->12 (AGPR 48+12=60), B live 24->12,
//    memory-clobber between passes stops CSE re-merging the loads.
// Peak arch ~55 <= 64, AGPR <= 64 -> no spill. 2 blocks/CU drift for pipe
// overlap. WRITE_SIZE = spill canary.
__global__ __launch_bounds__(512, 4) void gru_kernel(
    const float* __restrict__ x,
    const float* __restrict__ Whh1,
    const float* __restrict__ bih1, const float* __restrict__ bhh1,
    const char* __restrict__ wfrag,
    const float* __restrict__ bih2, const float* __restrict__ bhh2,
    const float* __restrict__ Wout, const float* __restrict__ bout,
    float* __restrict__ out)
{
  __shared__ char smem[SMEM_BYTES];
  const int tid = threadIdx.x;
  const int cw   = tid >> 6;        // wave = column owner (8 waves)
  const int lane = tid & 63;
  const int l15 = lane & 15;
  const int l16 = lane >> 4;        // 0..3
  const int hc0 = cw * 16;
  const int n0 = blockIdx.x * BN;

  f32x4 zq = {0.f, 0.f, 0.f, 0.f};
  asm("" : "+v"(zq));

  const int hrd = l15 * HSTRIDE + l16 * 16;
  const int hwr = (4 * l16) * HSTRIDE + (hc0 + l15) * 2;
  const int srow = tid >> 4, skp = tid & 15;
  const int xrd = XT_OFF + l15 * XSTRIDE + l16 * 16;
  const int xwr = XT_OFF + srow * XSTRIDE + skp * 4;
  const char* wsb = wfrag + cw * 12288 + lane * 16;          // Wih2 frags
  const char* wxb = wfrag + 98304 + cw * 3072 + lane * 16;   // Wih1 frags

  // ---- Whh1 B-frags resident (compiler places on acc side) ----
  s16x8 fw_hh1[4][3];
  const int gb0 = hc0, gb1 = 128 + hc0, gb2 = 256 + hc0;
  #pragma unroll
  for (int kf = 0; kf < 4; ++kf) {
    int kbase = kf * 32 + l16 * 8;
    #pragma unroll
    for (int cb = 0; cb < 3; ++cb) {
      int g = (cb == 0 ? gb0 : cb == 1 ? gb1 : gb2) + l15;
      const float* p1 = Whh1 + g * HID + kbase;
      s16x8 f1;
      #pragma unroll
      for (int j = 0; j < 8; j += 2) {
        unsigned u1 = cvtpk2(p1[j], p1[j + 1]);
        f1[j] = (short)u1; f1[j + 1] = (short)(u1 >> 16);
      }
      fw_hh1[kf][cb] = f1;
    }
  }
  const float nb_r  = -L2E * (bih1[gb0 + l15] + bhh1[gb0 + l15]);
  const float nb_z  = -L2E * (bih1[gb1 + l15] + bhh1[gb1 + l15]);
  const float b_ci  = bih1[gb2 + l15];
  const float b_ch  = bhh1[gb2 + l15];
  const float nb_r2 = -L2E * (bih2[gb0 + l15] + bhh2[gb0 + l15]);
  const float nb_z2 = -L2E * (bih2[gb1 + l15] + bhh2[gb1 + l15]);
  const float c_c2  = bih2[gb2 + l15];
  const float c_hc2 = bhh2[gb2 + l15];   // cell2 hc = bhh2_n (h==0)

  float h1reg[2][4];
  #pragma unroll
  for (int rf = 0; rf < 2; ++rf)
    #pragma unroll
    for (int j = 0; j < 4; ++j) h1reg[rf][j] = 0.f;

  const float2* xp0 = (const float2*)(x + (size_t)(n0 + srow) * 784 + 2 * skp);

  // ---- stage xt(0) into buf0 + zero H1 region ----
  {
    float2 v0 = make_float2(0.f, 0.f);
    if (skp < 14) v0 = *xp0;
    xp0 += 14;
    *(unsigned*)(smem + xwr) = cvtpk2(v0.x, v0.y);
  }
  ((int4*)(smem + H1_OFF))[tid] = make_int4(0, 0, 0, 0);
  if (tid < 32) ((int4*)(smem + H1_OFF))[tid + 512] = make_int4(0, 0, 0, 0);
  __syncthreads();

  #pragma unroll 1
  for (int t = 0; t < TSTEPS; ++t) {
    const int xb = (t & 1) * 2560;
    // ---- cell 1: K = 32 (x, B streamed) + 128 (h1, B resident) ----
    {
      s16x8 bx0 = *(const s16x8*)(wxb + 0);
      s16x8 bx1 = *(const s16x8*)(wxb + 1024);
      s16x8 bx2 = *(const s16x8*)(wxb + 2048);
      #pragma unroll
      for (int rf = 0; rf < 2; ++rf) {
        s16x8 ax = *(const s16x8*)(smem + xrd + xb + rf * 1280);
        f32x4 aR, aZ, aCi, aCh;
        aR  = __builtin_amdgcn_mfma_f32_16x16x32_bf16(ax, bx0, zq, 0, 0, 0);
        aZ  = __builtin_amdgcn_mfma_f32_16x16x32_bf16(ax, bx1, zq, 0, 0, 0);
        aCi = __builtin_amdgcn_mfma_f32_16x16x32_bf16(ax, bx2, zq, 0, 0, 0);
        #pragma unroll
        for (int kf = 0; kf < 4; ++kf) {
          s16x8 ah = *(const s16x8*)(smem + H1_OFF + hrd + rf * RFSTRIDE + kf * 64);
          aR = __builtin_amdgcn_mfma_f32_16x16x32_bf16(ah, fw_hh1[kf][0], aR, 0, 0, 0);
          aZ = __builtin_amdgcn_mfma_f32_16x16x32_bf16(ah, fw_hh1[kf][1], aZ, 0, 0, 0);
          aCh = (kf == 0)
              ? __builtin_amdgcn_mfma_f32_16x16x32_bf16(ah, fw_hh1[0][2], zq, 0, 0, 0)
              : __builtin_amdgcn_mfma_f32_16x16x32_bf16(ah, fw_hh1[kf][2], aCh, 0, 0, 0);
        }
        float h0v[4];
        #pragma unroll
        for (int j = 0; j < 4; ++j) {
          float r = sig_pre(aR[j], nb_r);
          float z = sig_pre(aZ[j], nb_z);
          float c = tanh_nc(fmaf(r, aCh[j] + b_ch, aCi[j] + b_ci));
          h0v[j] = fmaxf(fmaf(z, h1reg[rf][j] - c, c), 0.f);
        }
        unsigned pk01 = cvtpk2(h0v[0], h0v[1]);
        unsigned pk23 = cvtpk2(h0v[2], h0v[3]);
        *(short*)(smem + H0_OFF + hwr + rf * RFSTRIDE + 0 * HSTRIDE) = (short)pk01;
        *(short*)(smem + H0_OFF + hwr + rf * RFSTRIDE + 1 * HSTRIDE) = (short)(pk01 >> 16);
        *(short*)(smem + H0_OFF + hwr + rf * RFSTRIDE + 2 * HSTRIDE) = (short)pk23;
        *(short*)(smem + H0_OFF + hwr + rf * RFSTRIDE + 3 * HSTRIDE) = (short)(pk23 >> 16);
      }
    }
    __syncthreads();

    // ---- cell 2 (h==0): single-p passes, B streamed per pass ----
    float2 xv0 = make_float2(0.f, 0.f);
    const bool do_stage = (t + 1 < TSTEPS);
    if (do_stage && skp < 14) xv0 = *xp0;
    xp0 += 14;
    #pragma unroll
    for (int p = 0; p < 2; ++p) {
      f32x4 aR2, aZ2, aC2;
      #pragma unroll
      for (int kf = 0; kf < 4; ++kf) {
        s16x8 a0 = *(const s16x8*)(smem + H0_OFF + hrd + p * RFSTRIDE + kf * 64);
        s16x8 b0 = *(const s16x8*)(wsb + (kf * 3 + 0) * 1024);
        s16x8 b1 = *(const s16x8*)(wsb + (kf * 3 + 1) * 1024);
        s16x8 b2 = *(const s16x8*)(wsb + (kf * 3 + 2) * 1024);
        if (kf == 0) {
          aR2 = __builtin_amdgcn_mfma_f32_16x16x32_bf16(a0, b0, zq, 0, 0, 0);
          aZ2 = __builtin_amdgcn_mfma_f32_16x16x32_bf16(a0, b1, zq, 0, 0, 0);
          aC2 = __builtin_amdgcn_mfma_f32_16x16x32_bf16(a0, b2, zq, 0, 0, 0);
        } else {
          aR2 = __builtin_amdgcn_mfma_f32_16x16x32_bf16(a0, b0, aR2, 0, 0, 0);
          aZ2 = __builtin_amdgcn_mfma_f32_16x16x32_bf16(a0, b1, aZ2, 0, 0, 0);
          aC2 = __builtin_amdgcn_mfma_f32_16x16x32_bf16(a0, b2, aC2, 0, 0, 0);
        }
      }
      float hv[4];
      #pragma unroll
      for (int j = 0; j < 4; ++j) {
        float r2 = sig_pre(aR2[j], nb_r2);
        float z2 = sig_pre(aZ2[j], nb_z2);
        float c2 = tanh_nc(fmaf(r2, c_hc2, aC2[j] + c_c2));
        float h1n = fmaf(-z2, c2, c2);          // (1-z2)*c2
        h1reg[p][j] = h1n;
        hv[j] = h1n;
      }
      unsigned pk01 = cvtpk2(hv[0], hv[1]);
      unsigned pk23 = cvtpk2(hv[2], hv[3]);
      *(short*)(smem + H1_OFF + hwr + p * RFSTRIDE + 0 * HSTRIDE) = (short)pk01;
      *(short*)(smem + H1_OFF + hwr + p * RFSTRIDE + 1 * HSTRIDE) = (short)(pk01 >> 16);
      *(short*)(smem + H1_OFF + hwr + p * RFSTRIDE + 2 * HSTRIDE) = (short)pk23;
      *(short*)(smem + H1_OFF + hwr + p * RFSTRIDE + 3 * HSTRIDE) = (short)(pk23 >> 16);
      // keep the two passes' register footprints disjoint (stop load CSE)
      asm volatile("" ::: "memory");
    }
    if (do_stage) {
      const int xo = 2560 - xb;
      *(unsigned*)(smem + xwr + xo) = cvtpk2(xv0.x, xv0.y);
    }
    __syncthreads();
  }

  // ---- final projection: out = h1 @ Wout^T + bout ----
  float* houtf = (float*)smem;   // [32][132] overlay
  #pragma unroll
  for (int rf = 0; rf < 2; ++rf)
    #pragma unroll
    for (int j = 0; j < 4; ++j) {
      int row = rf * 16 + l16 * 4 + j;
      houtf[row * 132 + hc0 + l15] = h1reg[rf][j];
    }
  __syncthreads();
  if (tid < BN * 10) {
    int row = tid & 31;
    int o = tid >> 5;
    const float* hp = houtf + row * 132;
    const float* wp = Wout + o * HID;
    float s = bout[o];
    #pragma unroll 8
    for (int j2 = 0; j2 < HID; ++j2) s = fmaf(hp[j2], wp[j2], s);
    out[(size_t)(n0 + row) * 10 + o] = s;
  }
}

extern "C" void kernel_launch(void* const* d_in, const int* in_sizes, int n_in,
                              void* d_out, int out_size, void* d_ws, size_t ws_size,
                              hipStream_t stream) {
  const float* x    = (const float*)d_in[0];
  const float* Wih1 = (const float*)d_in[1];
  const float* Whh1 = (const float*)d_in[2];
  const float* bih1 = (const float*)d_in[3];
  const float* bhh1 = (const float*)d_in[4];
  const float* Wih2 = (const float*)d_in[5];
  // d_in[6] = Whh2: multiplied by zero hidden state in the reference -> unused
  const float* bih2 = (const float*)d_in[7];
  const float* bhh2 = (const float*)d_in[8];
  const float* Wout = (const float*)d_in[9];
  const float* bout = (const float*)d_in[10];
  char* ws = (char*)d_ws;   // 98304 (Wih2 frags) + 24576 (Wih1 frags)
  prep_w<<<120, 64, 0, stream>>>(Wih2, Wih1, ws);
  gru_kernel<<<NB / BN, 512, 0, stream>>>(x, Whh1, bih1, bhh1,
                                          ws, bih2, bhh2, Wout, bout,
                                          (float*)d_out);
}

// Round 15
// 145.720 us; speedup vs baseline: 2.5460x; 2.5460x over previous
//
#include <hip/hip_runtime.h>
#include <hip/hip_bf16.h>
#include <stdint.h>

#define HID 128
#define NB 16384
#define TSTEPS 28
#define BN 64

typedef __attribute__((ext_vector_type(8))) short s16x8;
typedef __attribute__((ext_vector_type(4))) float f32x4;

// ---- LDS map (padded-linear, R11) ----
//   H1 [64 rows x 272B]  17408B @ 0
//   H0 [64 rows x 272B]  17408B @ 17408
//   XT 2 bufs [64 x 80B]  5120B @ 34816 / 39936
//   WI2 frags [8cw][4kf][3cb][64 lane][16B] = 98304B @ 45056
#define H1_OFF 0
#define H0_OFF 17408
#define XT_OFF 34816
#define WI2_OFF 45056
#define SMEM_BYTES 143360
#define HSTRIDE 272
#define RFSTRIDE 4352   // 16*HSTRIDE
#define XSTRIDE 80

#define L2E 1.442695041f
#define TL2E 2.885390082f

__device__ __forceinline__ unsigned cvtpk2(float lo, float hi) {
  unsigned r;
  asm("v_cvt_pk_bf16_f32 %0, %1, %2" : "=v"(r) : "v"(lo), "v"(hi));
  return r;
}
__device__ __forceinline__ float sig_pre(float acc, float nb) {
  float e = __builtin_amdgcn_exp2f(fmaf(acc, -L2E, nb));
  return __builtin_amdgcn_rcpf(1.0f + e);
}
__device__ __forceinline__ float tanh_nc(float x) {
  float e2 = __builtin_amdgcn_exp2f(x * TL2E);
  float q = __builtin_amdgcn_rcpf(1.0f + e2);
  return fmaf(-2.0f, q, 1.0f);
}

// ---- Design ledger (R3..R14) ----
// Proven best: R12 (148us): 1024-thd, 16 waves (4/SIMD), LDS-resident Wih2,
// per-p cell2, no spill (VGPR 64/64 split), occ 44%. R13/R14 (global-streamed
// B at the 64-arch budget): scheduler hoists global loads -> live-range
// explosion -> 12-69MB scratch, FETCH 884MB (in-loop reload thrash). LESSON:
// at 4 waves/SIMD only LDS-sourced operands are pressure-safe.
// R12 pipe ledger: LDS read pipe dominates (~42 b128/wave/step, 24 = Wih2
// re-read per p). R15: cell2 BOTH-p single pass -> B read once, 30 reads
// (-29% LDS). Acc demand 72 (48 whh1 + 24 accs) needs accum_offset ~52/76 —
// compiler-chosen, arch demand ~45-50 fits. WRITE_SIZE = spill canary.
__global__ __launch_bounds__(1024, 1) void gru_kernel(
    const float* __restrict__ x,
    const float* __restrict__ Wih1, const float* __restrict__ Whh1,
    const float* __restrict__ bih1, const float* __restrict__ bhh1,
    const float* __restrict__ Wih2,
    const float* __restrict__ bih2, const float* __restrict__ bhh2,
    const float* __restrict__ Wout, const float* __restrict__ bout,
    float* __restrict__ out)
{
  __shared__ char smem[SMEM_BYTES];
  const int tid = threadIdx.x;
  const int wv16 = tid >> 6;
  const int mh   = wv16 >> 3;       // M-half: rows mh*32..+32
  const int cw   = wv16 & 7;        // column owner
  const int lane = tid & 63;
  const int l15 = lane & 15;
  const int l16 = lane >> 4;        // 0..3
  const int hc0 = cw * 16;
  const int n0 = blockIdx.x * BN;

  // persistent zero C-quad for MFMA chain seeding
  f32x4 zq = {0.f, 0.f, 0.f, 0.f};
  asm("" : "+v"(zq));

  // ---- thread-constant LDS bases ----
  const int hrd = (mh * 32 + l15) * HSTRIDE + l16 * 16;        // A-read base
  const int hwr = (mh * 32 + 4 * l16) * HSTRIDE + (hc0 + l15) * 2; // gate write
  const int srow = tid >> 4, skp = tid & 15;                   // 64 rows x 16
  const int xrd = XT_OFF + (mh * 32 + l15) * XSTRIDE + l16 * 16;
  const int xwr = XT_OFF + srow * XSTRIDE + skp * 4;
  const int wib = WI2_OFF + cw * 12288 + lane * 16;

  // ---- preload weights: fw_hh1/fw_ih1 in regs; Wih2 frags -> LDS ----
  s16x8 fw_hh1[4][3];
  s16x8 fw_ih1[3];
  const int gb0 = hc0, gb1 = 128 + hc0, gb2 = 256 + hc0;
  #pragma unroll
  for (int kf = 0; kf < 4; ++kf) {
    int kbase = kf * 32 + l16 * 8;
    #pragma unroll
    for (int cb = 0; cb < 3; ++cb) {
      int g = (cb == 0 ? gb0 : cb == 1 ? gb1 : gb2) + l15;
      const float* p1 = Whh1 + g * HID + kbase;
      s16x8 f1;
      #pragma unroll
      for (int j = 0; j < 8; j += 2) {
        unsigned u1 = cvtpk2(p1[j], p1[j + 1]);
        f1[j] = (short)u1; f1[j + 1] = (short)(u1 >> 16);
      }
      fw_hh1[kf][cb] = f1;
      if (mh == 0) {
        const float* p2 = Wih2 + g * HID + kbase;
        s16x8 f2;
        #pragma unroll
        for (int j = 0; j < 8; j += 2) {
          unsigned u2 = cvtpk2(p2[j], p2[j + 1]);
          f2[j] = (short)u2; f2[j + 1] = (short)(u2 >> 16);
        }
        *(s16x8*)(smem + wib + (kf * 3 + cb) * 1024) = f2;
      }
    }
  }
  {
    int kbase = l16 * 8;
    #pragma unroll
    for (int cb = 0; cb < 3; ++cb) {
      int g = (cb == 0 ? gb0 : cb == 1 ? gb1 : gb2) + l15;
      s16x8 f;
      #pragma unroll
      for (int j = 0; j < 8; ++j) {
        int k = kbase + j;
        f[j] = (k < 28) ? (short)cvtpk2(Wih1[g * 28 + k], 0.f) : (short)0;
      }
      fw_ih1[cb] = f;
    }
  }
  const float nb_r  = -L2E * (bih1[gb0 + l15] + bhh1[gb0 + l15]);
  const float nb_z  = -L2E * (bih1[gb1 + l15] + bhh1[gb1 + l15]);
  const float b_ci  = bih1[gb2 + l15];
  const float b_ch  = bhh1[gb2 + l15];
  const float nb_r2 = -L2E * (bih2[gb0 + l15] + bhh2[gb0 + l15]);
  const float nb_z2 = -L2E * (bih2[gb1 + l15] + bhh2[gb1 + l15]);
  const float c_c2  = bih2[gb2 + l15];
  const float c_hc2 = bhh2[gb2 + l15];   // cell2 hc = bhh2_n (h==0)

  float h1reg[2][4];
  #pragma unroll
  for (int rf = 0; rf < 2; ++rf)
    #pragma unroll
    for (int j = 0; j < 4; ++j) h1reg[rf][j] = 0.f;

  const float2* xp0 = (const float2*)(x + (size_t)(n0 + srow) * 784 + 2 * skp);

  // ---- stage xt(0) into buf0 + zero H1 region ----
  {
    float2 v0 = make_float2(0.f, 0.f);
    if (skp < 14) v0 = *xp0;
    xp0 += 14;   // -> t=1
    *(unsigned*)(smem + xwr) = cvtpk2(v0.x, v0.y);
  }
  ((int4*)(smem + H1_OFF))[tid] = make_int4(0, 0, 0, 0);
  if (tid < 64) ((int4*)(smem + H1_OFF))[tid + 1024] = make_int4(0, 0, 0, 0);
  __syncthreads();

  #pragma unroll 1
  for (int t = 0; t < TSTEPS; ++t) {
    const int xb = (t & 1) * 5120;
    // ---- cell 1: K = 32 (x) + 128 (h1) ----
    #pragma unroll
    for (int rf = 0; rf < 2; ++rf) {
      s16x8 ax = *(const s16x8*)(smem + xrd + xb + rf * 1280);
      f32x4 aR, aZ, aCi, aCh;
      aR  = __builtin_amdgcn_mfma_f32_16x16x32_bf16(ax, fw_ih1[0], zq, 0, 0, 0);
      aZ  = __builtin_amdgcn_mfma_f32_16x16x32_bf16(ax, fw_ih1[1], zq, 0, 0, 0);
      aCi = __builtin_amdgcn_mfma_f32_16x16x32_bf16(ax, fw_ih1[2], zq, 0, 0, 0);
      #pragma unroll
      for (int kf = 0; kf < 4; ++kf) {
        s16x8 ah = *(const s16x8*)(smem + H1_OFF + hrd + rf * RFSTRIDE + kf * 64);
        aR = __builtin_amdgcn_mfma_f32_16x16x32_bf16(ah, fw_hh1[kf][0], aR, 0, 0, 0);
        aZ = __builtin_amdgcn_mfma_f32_16x16x32_bf16(ah, fw_hh1[kf][1], aZ, 0, 0, 0);
        aCh = (kf == 0)
            ? __builtin_amdgcn_mfma_f32_16x16x32_bf16(ah, fw_hh1[0][2], zq, 0, 0, 0)
            : __builtin_amdgcn_mfma_f32_16x16x32_bf16(ah, fw_hh1[kf][2], aCh, 0, 0, 0);
      }
      float h0v[4];
      #pragma unroll
      for (int j = 0; j < 4; ++j) {
        float r = sig_pre(aR[j], nb_r);
        float z = sig_pre(aZ[j], nb_z);
        float c = tanh_nc(fmaf(r, aCh[j] + b_ch, aCi[j] + b_ci));
        h0v[j] = fmaxf(fmaf(z, h1reg[rf][j] - c, c), 0.f);
      }
      unsigned pk01 = cvtpk2(h0v[0], h0v[1]);
      unsigned pk23 = cvtpk2(h0v[2], h0v[3]);
      *(short*)(smem + H0_OFF + hwr + rf * RFSTRIDE + 0 * HSTRIDE) = (short)pk01;
      *(short*)(smem + H0_OFF + hwr + rf * RFSTRIDE + 1 * HSTRIDE) = (short)(pk01 >> 16);
      *(short*)(smem + H0_OFF + hwr + rf * RFSTRIDE + 2 * HSTRIDE) = (short)pk23;
      *(short*)(smem + H0_OFF + hwr + rf * RFSTRIDE + 3 * HSTRIDE) = (short)(pk23 >> 16);
    }
    __syncthreads();

    // ---- cell 2 (h==0): BOTH-p single pass, B-frags read once ----
    float2 xv0 = make_float2(0.f, 0.f);
    const bool do_stage = (t + 1 < TSTEPS);
    if (do_stage && skp < 14) xv0 = *xp0;
    xp0 += 14;
    {
      f32x4 aR2[2], aZ2[2], aC2[2];
      #pragma unroll
      for (int kf = 0; kf < 4; ++kf) {
        s16x8 a0 = *(const s16x8*)(smem + H0_OFF + hrd + kf * 64);
        s16x8 a1 = *(const s16x8*)(smem + H0_OFF + hrd + RFSTRIDE + kf * 64);
        s16x8 b0 = *(const s16x8*)(smem + wib + (kf * 3 + 0) * 1024);
        s16x8 b1 = *(const s16x8*)(smem + wib + (kf * 3 + 1) * 1024);
        s16x8 b2 = *(const s16x8*)(smem + wib + (kf * 3 + 2) * 1024);
        if (kf == 0) {
          aR2[0] = __builtin_amdgcn_mfma_f32_16x16x32_bf16(a0, b0, zq, 0, 0, 0);
          aR2[1] = __builtin_amdgcn_mfma_f32_16x16x32_bf16(a1, b0, zq, 0, 0, 0);
          aZ2[0] = __builtin_amdgcn_mfma_f32_16x16x32_bf16(a0, b1, zq, 0, 0, 0);
          aZ2[1] = __builtin_amdgcn_mfma_f32_16x16x32_bf16(a1, b1, zq, 0, 0, 0);
          aC2[0] = __builtin_amdgcn_mfma_f32_16x16x32_bf16(a0, b2, zq, 0, 0, 0);
          aC2[1] = __builtin_amdgcn_mfma_f32_16x16x32_bf16(a1, b2, zq, 0, 0, 0);
        } else {
          aR2[0] = __builtin_amdgcn_mfma_f32_16x16x32_bf16(a0, b0, aR2[0], 0, 0, 0);
          aR2[1] = __builtin_amdgcn_mfma_f32_16x16x32_bf16(a1, b0, aR2[1], 0, 0, 0);
          aZ2[0] = __builtin_amdgcn_mfma_f32_16x16x32_bf16(a0, b1, aZ2[0], 0, 0, 0);
          aZ2[1] = __builtin_amdgcn_mfma_f32_16x16x32_bf16(a1, b1, aZ2[1], 0, 0, 0);
          aC2[0] = __builtin_amdgcn_mfma_f32_16x16x32_bf16(a0, b2, aC2[0], 0, 0, 0);
          aC2[1] = __builtin_amdgcn_mfma_f32_16x16x32_bf16(a1, b2, aC2[1], 0, 0, 0);
        }
      }
      #pragma unroll
      for (int p = 0; p < 2; ++p) {
        float hv[4];
        #pragma unroll
        for (int j = 0; j < 4; ++j) {
          float r2 = sig_pre(aR2[p][j], nb_r2);
          float z2 = sig_pre(aZ2[p][j], nb_z2);
          float c2 = tanh_nc(fmaf(r2, c_hc2, aC2[p][j] + c_c2));
          float h1n = fmaf(-z2, c2, c2);          // (1-z2)*c2
          h1reg[p][j] = h1n;
          hv[j] = h1n;
        }
        unsigned pk01 = cvtpk2(hv[0], hv[1]);
        unsigned pk23 = cvtpk2(hv[2], hv[3]);
        *(short*)(smem + H1_OFF + hwr + p * RFSTRIDE + 0 * HSTRIDE) = (short)pk01;
        *(short*)(smem + H1_OFF + hwr + p * RFSTRIDE + 1 * HSTRIDE) = (short)(pk01 >> 16);
        *(short*)(smem + H1_OFF + hwr + p * RFSTRIDE + 2 * HSTRIDE) = (short)pk23;
        *(short*)(smem + H1_OFF + hwr + p * RFSTRIDE + 3 * HSTRIDE) = (short)(pk23 >> 16);
      }
    }
    if (do_stage) {
      const int xo = 5120 - xb;   // other buffer
      *(unsigned*)(smem + xwr + xo) = cvtpk2(xv0.x, xv0.y);
    }
    __syncthreads();
  }

  // ---- final projection: out = h1 @ Wout^T + bout (fp32 h1 from regs) ----
  float* houtf = (float*)smem;   // [64][132] overlay = 33792 B
  #pragma unroll
  for (int rf = 0; rf < 2; ++rf)
    #pragma unroll
    for (int j = 0; j < 4; ++j) {
      int row = mh * 32 + rf * 16 + l16 * 4 + j;
      houtf[row * 132 + hc0 + l15] = h1reg[rf][j];
    }
  __syncthreads();
  if (tid < BN * 10) {
    int row = tid & 63;
    int o = tid >> 6;
    const float* hp = houtf + row * 132;
    const float* wp = Wout + o * HID;
    float s = bout[o];
    #pragma unroll 8
    for (int j2 = 0; j2 < HID; ++j2) s = fmaf(hp[j2], wp[j2], s);
    out[(size_t)(n0 + row) * 10 + o] = s;
  }
}

extern "C" void kernel_launch(void* const* d_in, const int* in_sizes, int n_in,
                              void* d_out, int out_size, void* d_ws, size_t ws_size,
                              hipStream_t stream) {
  const float* x    = (const float*)d_in[0];
  const float* Wih1 = (const float*)d_in[1];
  const float* Whh1 = (const float*)d_in[2];
  const float* bih1 = (const float*)d_in[3];
  const float* bhh1 = (const float*)d_in[4];
  const float* Wih2 = (const float*)d_in[5];
  // d_in[6] = Whh2: multiplied by zero hidden state in the reference -> unused
  const float* bih2 = (const float*)d_in[7];
  const float* bhh2 = (const float*)d_in[8];
  const float* Wout = (const float*)d_in[9];
  const float* bout = (const float*)d_in[10];
  gru_kernel<<<NB / BN, 1024, 0, stream>>>(x, Wih1, Whh1, bih1, bhh1,
                                           Wih2, bih2, bhh2, Wout, bout,
                                           (float*)d_out);
}